// Round 7
// baseline (421.950 us; speedup 1.0000x reference)
//
#include <hip/hip_runtime.h>

#define H 128

typedef __attribute__((ext_vector_type(8))) short bf16x8;
typedef __attribute__((ext_vector_type(4))) float f32x4;

__device__ __forceinline__ unsigned short f2bf(float f) {
    unsigned u = __float_as_uint(f);
    u += 0x7FFFu + ((u >> 16) & 1u);
    return (unsigned short)(u >> 16);
}
__device__ __forceinline__ float bflo(unsigned v) { return __uint_as_float(v << 16); }
__device__ __forceinline__ float bfhi(unsigned v) { return __uint_as_float(v & 0xFFFF0000u); }

// ---- CSR build via 2-level bucket sort ----------------------------------
__global__ void __launch_bounds__(256) k_bhist(const int* __restrict__ ei,
                                               int* __restrict__ bhist, int E) {
    __shared__ int h[512];
    int t = threadIdx.x;
    h[t] = 0; h[t + 256] = 0;
    __syncthreads();
    int stride = gridDim.x * 256;
    for (int e = blockIdx.x * 256 + t; e < E; e += stride)
        atomicAdd(&h[ei[E + e] >> 8], 1);
    __syncthreads();
    for (int u = t; u < 512; u += 256) {
        int v = h[u];
        if (v) atomicAdd(&bhist[u], v);
    }
}

__global__ void k_bscan(const int* __restrict__ bhist, int* __restrict__ bbase,
                        int* __restrict__ gcur) {
    __shared__ int sh[512];
    int t = threadIdx.x;
    int v = bhist[t];
    sh[t] = v;
    __syncthreads();
    for (int off = 1; off < 512; off <<= 1) {
        int u = (t >= off) ? sh[t - off] : 0;
        __syncthreads();
        sh[t] += u;
        __syncthreads();
    }
    int ex = sh[t] - v;
    bbase[t] = ex;
    gcur[t] = ex;
    if (t == 511) bbase[512] = sh[t];
}

__global__ void __launch_bounds__(256) k_scatter(const int* __restrict__ ei,
        int* __restrict__ gcur, int2* __restrict__ tmp_sd, int E) {
    __shared__ int hist[512], base[512], fill[512];
    int blk = blockIdx.x, t = threadIdx.x;
    int chunk = (E + gridDim.x - 1) / gridDim.x;
    int c0 = blk * chunk;
    int c1 = c0 + chunk; if (c1 > E) c1 = E;
    hist[t] = 0; hist[t + 256] = 0;
    __syncthreads();
    for (int e = c0 + t; e < c1; e += 256)
        atomicAdd(&hist[ei[E + e] >> 8], 1);
    __syncthreads();
    for (int u = t; u < 512; u += 256) {
        int h = hist[u];
        base[u] = h ? atomicAdd(&gcur[u], h) : 0;
        fill[u] = 0;
    }
    __syncthreads();
    for (int e = c0 + t; e < c1; e += 256) {
        int d = ei[E + e], s = ei[e];
        int bb = d >> 8;
        int p = base[bb] + atomicAdd(&fill[bb], 1);
        tmp_sd[p] = make_int2(s, d);
    }
}

__global__ void __launch_bounds__(256) k_csrA(const int2* __restrict__ tmp_sd,
        const int* __restrict__ bbase, int* __restrict__ rp,
        float* __restrict__ dinv, float* __restrict__ invdeg, int N, int E) {
    __shared__ int cnt[256];
    __shared__ int sh[256];
    int b = blockIdx.x, t = threadIdx.x;
    int e0 = bbase[b], e1 = bbase[b + 1];
    cnt[t] = 0;
    __syncthreads();
    for (int e = e0 + t; e < e1; e += 256)
        atomicAdd(&cnt[tmp_sd[e].y & 255], 1);
    __syncthreads();
    int v = cnt[t];
    sh[t] = v;
    __syncthreads();
    for (int off = 1; off < 256; off <<= 1) {
        int u = (t >= off) ? sh[t - off] : 0;
        __syncthreads();
        sh[t] += u;
        __syncthreads();
    }
    int gid = (b << 8) + t;
    if (gid < N) {
        rp[gid] = e0 + sh[t] - v;
        float dg = (float)(v + 1);
        dinv[gid] = rsqrtf(dg);
        invdeg[gid] = 1.0f / dg;
    }
    if (b == 0 && t == 0) rp[N] = E;
}

__global__ void __launch_bounds__(256) k_csrB(const int2* __restrict__ tmp_sd,
        const int* __restrict__ bbase, const int* __restrict__ rp,
        const float* __restrict__ dinv, int* __restrict__ csrc,
        float* __restrict__ cw, int N) {
    __shared__ int fill[256];
    __shared__ float ld[256];
    int b = blockIdx.x, t = threadIdx.x;
    int e0 = bbase[b], e1 = bbase[b + 1];
    int gid = (b << 8) + t;
    fill[t] = (gid < N) ? rp[gid] : 0;
    ld[t] = (gid < N) ? dinv[gid] : 0.0f;
    __syncthreads();
    for (int e = e0 + t; e < e1; e += 256) {
        int2 sd = tmp_sd[e];
        int l = sd.y & 255;
        int p = atomicAdd(&fill[l], 1);
        csrc[p] = sd.x;
        cw[p] = dinv[sd.x] * ld[l];
    }
}

// ---- dtype prep ---------------------------------------------------------
__global__ void k_xbf(const float* __restrict__ x, unsigned* __restrict__ xb, int n2) {
    int i = blockIdx.x * blockDim.x + threadIdx.x;
    if (i < n2) {
        float2 v = ((const float2*)x)[i];
        xb[i] = (unsigned)f2bf(v.x) | ((unsigned)f2bf(v.y) << 16);
    }
}

// merged weight prep (unchanged)
__global__ void k_wprep(const float* __restrict__ W, const float* __restrict__ b,
                        const float* __restrict__ r3w, const float* __restrict__ r3b,
                        const float* __restrict__ r2w, const float* __restrict__ r2b,
                        unsigned short* __restrict__ Wt, unsigned short* __restrict__ WRb,
                        float* __restrict__ bias2) {
    int idx = blockIdx.x * blockDim.x + threadIdx.x;
    if (idx < 114688) {
        int k = idx >> 14;
        int f = (idx >> 7) & 127;
        int h = idx & 127;
        Wt[(k << 14) + (h << 7) + f] = f2bf(W[idx]);
        return;
    }
    int idx2 = idx - 114688;
    if (idx2 < 14336) {
        int j = idx2 & 7;
        int lane = (idx2 >> 3) & 63;
        int kk = (idx2 >> 9) & 3;
        int k = idx2 >> 11;
        int c = lane & 15;
        int off = ((lane >> 4) << 3) + j;
        int f = kk * 32 + (off >> 1) + ((off & 1) << 4);
        int ck = (k < 5) ? 3 : 2;
        float s = 0.0f;
        if (c < ck) {
            const float* R = (k < 5) ? (r3w + (size_t)(k * 3 + c) * H)
                                     : (r2w + (size_t)((k - 5) * 2 + c) * H);
            const float* Wk = W + (k << 14) + (f << 7);
            for (int h = 0; h < H; ++h) s += Wk[h] * R[h];
        }
        WRb[idx2] = f2bf(s);
    } else if (idx2 < 14336 + 32) {
        int c32 = idx2 - 14336;
        int k = c32 >> 2, c = c32 & 3;
        int ck = (k < 5) ? 3 : 2;
        float t = 0.0f;
        if (c < ck) {
            const float* R = (k < 5) ? (r3w + (size_t)(k * 3 + c) * H)
                                     : (r2w + (size_t)((k - 5) * 2 + c) * H);
            const float* bk = b + k * H;
            for (int h = 0; h < H; ++h) t += bk[h] * R[h];
            t += (k < 5) ? r3b[k * 3 + c] : r2b[(k - 5) * 2 + c];
        }
        bias2[c32] = t;
    }
}

// ---- aggregation 1: px = P_hat @ x --------------------------------------
// wave/node; 16 lanes x 16B = one row; unroll-8: two gathers in flight
__global__ void __launch_bounds__(256) k_px(const unsigned* __restrict__ xb,
        const int* __restrict__ rp, const int* __restrict__ csrc,
        const float* __restrict__ cw, const float* __restrict__ invdeg,
        unsigned* __restrict__ pxb, int N) {
    int lane = threadIdx.x & 63;
    int wv = threadIdx.x >> 6;
    int i = blockIdx.x * 4 + wv;
    if (i >= N) return;
    int grp = lane >> 4, sub = lane & 15;
    const unsigned* xbs = xb + sub * 4;
    int s = rp[i], e = rp[i + 1];
    float acc[8] = {0.f, 0.f, 0.f, 0.f, 0.f, 0.f, 0.f, 0.f};
    float acb[8] = {0.f, 0.f, 0.f, 0.f, 0.f, 0.f, 0.f, 0.f};
    for (int base = s; base < e; base += 64) {
        int el = base + lane;
        bool ok = el < e;
        int j_l = ok ? csrc[el] : 0;
        float w_l = ok ? cw[el] : 0.0f;
        int cnt = e - base; if (cnt > 64) cnt = 64;
        for (int t = 0; t < cnt; t += 8) {
            int i0 = t + grp, i1 = t + 4 + grp;
            int jj0 = __shfl(j_l, i0);   float ww0 = __shfl(w_l, i0);
            int jj1 = __shfl(j_l, i1);   float ww1 = __shfl(w_l, i1);
            const uint4 v0 = *(const uint4*)(xbs + (size_t)jj0 * 64);
            const uint4 v1 = *(const uint4*)(xbs + (size_t)jj1 * 64);
            acc[0] += ww0 * bflo(v0.x); acc[1] += ww0 * bfhi(v0.x);
            acc[2] += ww0 * bflo(v0.y); acc[3] += ww0 * bfhi(v0.y);
            acc[4] += ww0 * bflo(v0.z); acc[5] += ww0 * bfhi(v0.z);
            acc[6] += ww0 * bflo(v0.w); acc[7] += ww0 * bfhi(v0.w);
            acb[0] += ww1 * bflo(v1.x); acb[1] += ww1 * bfhi(v1.x);
            acb[2] += ww1 * bflo(v1.y); acb[3] += ww1 * bfhi(v1.y);
            acb[4] += ww1 * bflo(v1.z); acb[5] += ww1 * bfhi(v1.z);
            acb[6] += ww1 * bflo(v1.w); acb[7] += ww1 * bfhi(v1.w);
        }
    }
#pragma unroll
    for (int r = 0; r < 8; ++r) {
        acc[r] += acb[r];
        acc[r] += __shfl_xor(acc[r], 16);
        acc[r] += __shfl_xor(acc[r], 32);
    }
    if (grp == 0) {
        const uint4 v = *(const uint4*)(xbs + (size_t)i * 64);
        float id = invdeg[i];
        uint4 o;
        o.x = (unsigned)f2bf(acc[0] + id * bflo(v.x)) | ((unsigned)f2bf(acc[1] + id * bfhi(v.x)) << 16);
        o.y = (unsigned)f2bf(acc[2] + id * bflo(v.y)) | ((unsigned)f2bf(acc[3] + id * bfhi(v.y)) << 16);
        o.z = (unsigned)f2bf(acc[4] + id * bflo(v.z)) | ((unsigned)f2bf(acc[5] + id * bfhi(v.z)) << 16);
        o.w = (unsigned)f2bf(acc[6] + id * bflo(v.w)) | ((unsigned)f2bf(acc[7] + id * bfhi(v.w)) << 16);
        *(uint4*)(pxb + (size_t)i * 64 + sub * 4) = o;
    }
}

// ---- GEMM: u = (relu(px@Wk + bk)) @ WR_k --------------------------------
// unchanged core (LDS-staged B); epilogue now packs u to bf16 [N,32]
__global__ void __launch_bounds__(256, 2) k_gemm(const unsigned short* __restrict__ pxb,
        const unsigned short* __restrict__ Wt, const float* __restrict__ gb,
        const unsigned short* __restrict__ WRb, unsigned* __restrict__ uallb, int N) {
    __shared__ __align__(16) unsigned short Bs[128 * 136];
    __shared__ __align__(16) unsigned h1w[4][2560];
    int k = blockIdx.y;
    int wv = threadIdx.x >> 6;
    int lane = threadIdx.x & 63;
    int quad = lane >> 4, l16 = lane & 15;

    {
        const unsigned short* src = Wt + (k << 14);
        int t = threadIdx.x;
#pragma unroll
        for (int i = 0; i < 8; ++i) {
            int li = i * 256 + t;
            int f = li >> 4, seg = li & 15;
            *(bf16x8*)(Bs + f * 136 + seg * 8) = *(const bf16x8*)(src + f * 128 + seg * 8);
        }
    }
    __syncthreads();

    unsigned* wl = &h1w[wv][0];
    int rowbase = blockIdx.x * 512 + wv * 32;

    bf16x8 af[2][2][4];
    {
        int rb0 = rowbase;
#pragma unroll
        for (int rb = 0; rb < 2; ++rb) {
            int r = rb0 + rb * 16 + l16;
            if (r >= N) r = N - 1;
#pragma unroll
            for (int kk = 0; kk < 4; ++kk)
                af[0][rb][kk] = *(const bf16x8*)(pxb + (size_t)r * H + kk * 32 + quad * 8);
        }
    }

    float bi[4][2];
#pragma unroll
    for (int p = 0; p < 4; ++p) {
        bi[p][0] = gb[k * H + 32 * p + l16];
        bi[p][1] = gb[k * H + 32 * p + 16 + l16];
    }
    bf16x8 bw[4];
#pragma unroll
    for (int kk = 0; kk < 4; ++kk)
        bw[kk] = *(const bf16x8*)(WRb + (size_t)((k * 4 + kk) * 64 + lane) * 8);

    for (int t = 0; t < 4; ++t) {
        if (t < 3) {
            int rb0 = rowbase + (t + 1) * 128;
#pragma unroll
            for (int rb = 0; rb < 2; ++rb) {
                int r = rb0 + rb * 16 + l16;
                if (r >= N) r = N - 1;
#pragma unroll
                for (int kk = 0; kk < 4; ++kk)
                    af[(t + 1) & 1][rb][kk] = *(const bf16x8*)(pxb + (size_t)r * H + kk * 32 + quad * 8);
            }
        }
        int row0 = rowbase + t * 128;
#pragma unroll
        for (int p = 0; p < 4; ++p) {
            f32x4 cacc[2][2] = {};
#pragma unroll
            for (int kk = 0; kk < 4; ++kk) {
                bf16x8 b0 = *(const bf16x8*)(Bs + (32 * p + l16) * 136 + kk * 32 + quad * 8);
                bf16x8 b1 = *(const bf16x8*)(Bs + (32 * p + 16 + l16) * 136 + kk * 32 + quad * 8);
#pragma unroll
                for (int rb = 0; rb < 2; ++rb) {
                    cacc[rb][0] = __builtin_amdgcn_mfma_f32_16x16x32_bf16(af[t & 1][rb][kk], b0, cacc[rb][0], 0, 0, 0);
                    cacc[rb][1] = __builtin_amdgcn_mfma_f32_16x16x32_bf16(af[t & 1][rb][kk], b1, cacc[rb][1], 0, 0, 0);
                }
            }
#pragma unroll
            for (int rb = 0; rb < 2; ++rb)
#pragma unroll
                for (int r = 0; r < 4; ++r) {
                    float lo = fmaxf(cacc[rb][0][r] + bi[p][0], 0.0f);
                    float hi = fmaxf(cacc[rb][1][r] + bi[p][1], 0.0f);
                    unsigned pk = (unsigned)f2bf(lo) | ((unsigned)f2bf(hi) << 16);
                    wl[(p * 32 + rb * 16 + quad * 4 + r) * 20 + l16] = pk;
                }
        }
        // projection GEMM (K=128 permuted), wave-local, no barrier
        f32x4 u0 = {}, u1 = {};
#pragma unroll
        for (int kk = 0; kk < 4; ++kk) {
            bf16x8 a0 = *(const bf16x8*)(wl + (kk * 32 + l16) * 20 + quad * 4);
            bf16x8 a1 = *(const bf16x8*)(wl + (kk * 32 + 16 + l16) * 20 + quad * 4);
            u0 = __builtin_amdgcn_mfma_f32_16x16x32_bf16(a0, bw[kk], u0, 0, 0, 0);
            u1 = __builtin_amdgcn_mfma_f32_16x16x32_bf16(a1, bw[kk], u1, 0, 0, 0);
        }
        // pack col pairs to bf16 and store: cols (l16,l16+1) for even l16<4
#pragma unroll
        for (int r = 0; r < 4; ++r) {
            float p0 = __shfl_xor(u0[r], 1);
            float p1 = __shfl_xor(u1[r], 1);
            if ((l16 & 1) == 0 && l16 < 4) {
                unsigned pk0 = (unsigned)f2bf(u0[r]) | ((unsigned)f2bf(p0) << 16);
                unsigned pk1 = (unsigned)f2bf(u1[r]) | ((unsigned)f2bf(p1) << 16);
                int ra = row0 + quad * 4 + r;
                int rb2 = ra + 16;
                int ci = k * 2 + (l16 >> 1);
                if (ra < N) uallb[(size_t)ra * 16 + ci] = pk0;
                if (rb2 < N) uallb[(size_t)rb2 * 16 + ci] = pk1;
            }
        }
    }
}

// ---- aggregation 2 + softmax (bf16 u, 4 lanes/row, 16 edges/instr) ------
__global__ void __launch_bounds__(256) k_out(const unsigned* __restrict__ uallb,
        const int* __restrict__ rp, const int* __restrict__ csrc,
        const float* __restrict__ cw, const float* __restrict__ invdeg,
        const float* __restrict__ bias2, float* __restrict__ out, int N) {
    int lane = threadIdx.x & 63;
    int wv = threadIdx.x >> 6;
    int i = blockIdx.x * 4 + wv;
    if (i >= N) return;
    int grp = lane >> 2, sub = lane & 3;
    const unsigned* us = uallb + sub * 4;
    int s = rp[i], e = rp[i + 1];
    float acc[8] = {0.f, 0.f, 0.f, 0.f, 0.f, 0.f, 0.f, 0.f};
    for (int base = s; base < e; base += 64) {
        int el = base + lane;
        bool ok = el < e;
        int j_l = ok ? csrc[el] : 0;
        float w_l = ok ? cw[el] : 0.0f;
        int cnt = e - base; if (cnt > 64) cnt = 64;
        for (int t = 0; t < cnt; t += 16) {
            int idx = t + grp;
            int jj = __shfl(j_l, idx);
            float ww = __shfl(w_l, idx);
            const uint4 v = *(const uint4*)(us + (size_t)jj * 16);
            acc[0] += ww * bflo(v.x); acc[1] += ww * bfhi(v.x);
            acc[2] += ww * bflo(v.y); acc[3] += ww * bfhi(v.y);
            acc[4] += ww * bflo(v.z); acc[5] += ww * bfhi(v.z);
            acc[6] += ww * bflo(v.w); acc[7] += ww * bfhi(v.w);
        }
    }
#pragma unroll
    for (int r = 0; r < 8; ++r) {
        acc[r] += __shfl_xor(acc[r], 4);
        acc[r] += __shfl_xor(acc[r], 8);
        acc[r] += __shfl_xor(acc[r], 16);
        acc[r] += __shfl_xor(acc[r], 32);
    }
    if (grp == 0) {   // lanes 0..3; lane sub owns branches 2*sub(, 2*sub+1)
        const uint4 sv = *(const uint4*)(us + (size_t)i * 16);
        float id = invdeg[i];
        float4 bA = *(const float4*)(bias2 + sub * 8);
        float4 bB = *(const float4*)(bias2 + sub * 8 + 4);
        float w0 = acc[0] + id * bflo(sv.x) + bA.x;
        float w1 = acc[1] + id * bfhi(sv.x) + bA.y;
        float w2 = acc[2] + id * bflo(sv.y) + bA.z;
        float w4 = acc[4] + id * bflo(sv.z) + bB.x;
        float w5 = acc[5] + id * bfhi(sv.z) + bB.y;
        float w6 = acc[6] + id * bflo(sv.w) + bB.z;
        auto wr = [&](int b, float v0, float v1, float v2) {
            int ck = (b < 5) ? 3 : 2;
            float mx = fmaxf(v0, v1);
            if (ck == 3) mx = fmaxf(mx, v2);
            float e0 = __expf(v0 - mx), e1 = __expf(v1 - mx);
            float e2 = (ck == 3) ? __expf(v2 - mx) : 0.0f;
            float inv = 1.0f / (e0 + e1 + e2);
            size_t bb = (b < 5) ? (size_t)b * 3 * N + (size_t)i * 3
                                : (size_t)15 * N + (size_t)(b - 5) * 2 * N + (size_t)i * 2;
            out[bb] = e0 * inv;
            out[bb + 1] = e1 * inv;
            if (ck == 3) out[bb + 2] = e2 * inv;
        };
        wr(sub * 2, w0, w1, w2);
        if (sub < 3) wr(sub * 2 + 1, w4, w5, w6);
    }
}

// ---- launch -------------------------------------------------------------
extern "C" void kernel_launch(void* const* d_in, const int* in_sizes, int n_in,
                              void* d_out, int out_size, void* d_ws, size_t ws_size,
                              hipStream_t stream) {
    (void)n_in; (void)out_size; (void)ws_size;
    const float* x   = (const float*)d_in[0];
    const int*   ei  = (const int*)d_in[1];
    const float* gw  = (const float*)d_in[2];
    const float* gb  = (const float*)d_in[3];
    const float* r3w = (const float*)d_in[4];
    const float* r3b = (const float*)d_in[5];
    const float* r2w = (const float*)d_in[6];
    const float* r2b = (const float*)d_in[7];
    float* out = (float*)d_out;
    int N = in_sizes[0] / H;   // 100000
    int E = in_sizes[1] / 2;   // 1600000
    int NB = (N + 255) >> 8;   // 391 buckets

    char* p = (char*)d_ws;
    auto alloc = [&](size_t bytes) {
        char* q = p;
        p += (bytes + 255) & ~(size_t)255;
        return q;
    };
    unsigned*       xb     = (unsigned*)alloc((size_t)N * 64 * 4);
    unsigned*       pxb    = (unsigned*)alloc((size_t)N * 64 * 4);
    unsigned short* Wt     = (unsigned short*)alloc((size_t)7 * 16384 * 2);
    unsigned short* WRb    = (unsigned short*)alloc((size_t)14336 * 2);
    float*          bias2  = (float*)alloc(32 * 4);
    int*            bhist  = (int*)alloc(512 * 4);
    int*            bbase  = (int*)alloc(513 * 4);
    int*            gcur   = (int*)alloc(512 * 4);
    int2*           tmp_sd = (int2*)alloc((size_t)E * 8);
    int*            rp     = (int*)alloc((size_t)(N + 1) * 4);
    float*          dinv   = (float*)alloc((size_t)N * 4);
    float*          invdeg = (float*)alloc((size_t)N * 4);
    int*            csrc   = (int*)alloc((size_t)E * 4);
    float*          cw     = (float*)alloc((size_t)E * 4);
    unsigned*       uallb  = (unsigned*)alloc((size_t)N * 16 * 4);   // bf16 [N,32]

    hipMemsetAsync(bhist, 0, 512 * 4, stream);
    k_bhist<<<256, 256, 0, stream>>>(ei, bhist, E);
    k_bscan<<<1, 512, 0, stream>>>(bhist, bbase, gcur);
    k_scatter<<<256, 256, 0, stream>>>(ei, gcur, tmp_sd, E);
    k_csrA<<<NB, 256, 0, stream>>>(tmp_sd, bbase, rp, dinv, invdeg, N, E);
    k_csrB<<<NB, 256, 0, stream>>>(tmp_sd, bbase, rp, dinv, csrc, cw, N);
    k_xbf<<<(N * 64 + 255) / 256, 256, 0, stream>>>(x, xb, N * 64);
    k_wprep<<<(114688 + 14368 + 255) / 256, 256, 0, stream>>>(gw, gb, r3w, r3b, r2w, r2b,
                                                              Wt, WRb, bias2);
    k_px<<<(N + 3) / 4, 256, 0, stream>>>(xb, rp, csrc, cw, invdeg, pxb, N);
    dim3 gg((N + 511) / 512, 7);
    k_gemm<<<gg, 256, 0, stream>>>((const unsigned short*)pxb, Wt, gb, WRb, uallb, N);
    k_out<<<(N + 3) / 4, 256, 0, stream>>>(uallb, rp, csrc, cw, invdeg, bias2, out, N);
}

// Round 8
// 333.647 us; speedup vs baseline: 1.2647x; 1.2647x over previous
//
#include <hip/hip_runtime.h>

#define H 128

typedef __attribute__((ext_vector_type(8))) short bf16x8;
typedef __attribute__((ext_vector_type(4))) float f32x4;

__device__ __forceinline__ unsigned short f2bf(float f) {
    unsigned u = __float_as_uint(f);
    u += 0x7FFFu + ((u >> 16) & 1u);
    return (unsigned short)(u >> 16);
}
__device__ __forceinline__ float bflo(unsigned v) { return __uint_as_float(v << 16); }
__device__ __forceinline__ float bfhi(unsigned v) { return __uint_as_float(v & 0xFFFF0000u); }

// ---- CSR build via 2-level bucket sort ----------------------------------
__global__ void __launch_bounds__(256) k_bhist(const int* __restrict__ ei,
                                               int* __restrict__ bhist, int E) {
    __shared__ int h[512];
    int t = threadIdx.x;
    h[t] = 0; h[t + 256] = 0;
    __syncthreads();
    int stride = gridDim.x * 256;
    for (int e = blockIdx.x * 256 + t; e < E; e += stride)
        atomicAdd(&h[ei[E + e] >> 8], 1);
    __syncthreads();
    for (int u = t; u < 512; u += 256) {
        int v = h[u];
        if (v) atomicAdd(&bhist[u], v);
    }
}

__global__ void k_bscan(const int* __restrict__ bhist, int* __restrict__ bbase,
                        int* __restrict__ gcur) {
    __shared__ int sh[512];
    int t = threadIdx.x;
    int v = bhist[t];
    sh[t] = v;
    __syncthreads();
    for (int off = 1; off < 512; off <<= 1) {
        int u = (t >= off) ? sh[t - off] : 0;
        __syncthreads();
        sh[t] += u;
        __syncthreads();
    }
    int ex = sh[t] - v;
    bbase[t] = ex;
    gcur[t] = ex;
    if (t == 511) bbase[512] = sh[t];
}

__global__ void __launch_bounds__(256) k_scatter(const int* __restrict__ ei,
        int* __restrict__ gcur, int2* __restrict__ tmp_sd, int E) {
    __shared__ int hist[512], base[512], fill[512];
    int blk = blockIdx.x, t = threadIdx.x;
    int chunk = (E + gridDim.x - 1) / gridDim.x;
    int c0 = blk * chunk;
    int c1 = c0 + chunk; if (c1 > E) c1 = E;
    hist[t] = 0; hist[t + 256] = 0;
    __syncthreads();
    for (int e = c0 + t; e < c1; e += 256)
        atomicAdd(&hist[ei[E + e] >> 8], 1);
    __syncthreads();
    for (int u = t; u < 512; u += 256) {
        int h = hist[u];
        base[u] = h ? atomicAdd(&gcur[u], h) : 0;
        fill[u] = 0;
    }
    __syncthreads();
    for (int e = c0 + t; e < c1; e += 256) {
        int d = ei[E + e], s = ei[e];
        int bb = d >> 8;
        int p = base[bb] + atomicAdd(&fill[bb], 1);
        tmp_sd[p] = make_int2(s, d);
    }
}

__global__ void __launch_bounds__(256) k_csrA(const int2* __restrict__ tmp_sd,
        const int* __restrict__ bbase, int* __restrict__ rp,
        float* __restrict__ dinv, float* __restrict__ invdeg, int N, int E) {
    __shared__ int cnt[256];
    __shared__ int sh[256];
    int b = blockIdx.x, t = threadIdx.x;
    int e0 = bbase[b], e1 = bbase[b + 1];
    cnt[t] = 0;
    __syncthreads();
    for (int e = e0 + t; e < e1; e += 256)
        atomicAdd(&cnt[tmp_sd[e].y & 255], 1);
    __syncthreads();
    int v = cnt[t];
    sh[t] = v;
    __syncthreads();
    for (int off = 1; off < 256; off <<= 1) {
        int u = (t >= off) ? sh[t - off] : 0;
        __syncthreads();
        sh[t] += u;
        __syncthreads();
    }
    int gid = (b << 8) + t;
    if (gid < N) {
        rp[gid] = e0 + sh[t] - v;
        float dg = (float)(v + 1);
        dinv[gid] = rsqrtf(dg);
        invdeg[gid] = 1.0f / dg;
    }
    if (b == 0 && t == 0) rp[N] = E;
}

__global__ void __launch_bounds__(256) k_csrB(const int2* __restrict__ tmp_sd,
        const int* __restrict__ bbase, const int* __restrict__ rp,
        const float* __restrict__ dinv, int* __restrict__ csrc,
        float* __restrict__ cw, int N) {
    __shared__ int fill[256];
    __shared__ float ld[256];
    int b = blockIdx.x, t = threadIdx.x;
    int e0 = bbase[b], e1 = bbase[b + 1];
    int gid = (b << 8) + t;
    fill[t] = (gid < N) ? rp[gid] : 0;
    ld[t] = (gid < N) ? dinv[gid] : 0.0f;
    __syncthreads();
    for (int e = e0 + t; e < e1; e += 256) {
        int2 sd = tmp_sd[e];
        int l = sd.y & 255;
        int p = atomicAdd(&fill[l], 1);
        csrc[p] = sd.x;
        cw[p] = dinv[sd.x] * ld[l];
    }
}

// ---- dtype prep (also reused as fp32->bf16 pack converter) --------------
__global__ void k_xbf(const float* __restrict__ x, unsigned* __restrict__ xb, int n2) {
    int i = blockIdx.x * blockDim.x + threadIdx.x;
    if (i < n2) {
        float2 v = ((const float2*)x)[i];
        xb[i] = (unsigned)f2bf(v.x) | ((unsigned)f2bf(v.y) << 16);
    }
}

// merged weight prep (unchanged)
__global__ void k_wprep(const float* __restrict__ W, const float* __restrict__ b,
                        const float* __restrict__ r3w, const float* __restrict__ r3b,
                        const float* __restrict__ r2w, const float* __restrict__ r2b,
                        unsigned short* __restrict__ Wt, unsigned short* __restrict__ WRb,
                        float* __restrict__ bias2) {
    int idx = blockIdx.x * blockDim.x + threadIdx.x;
    if (idx < 114688) {
        int k = idx >> 14;
        int f = (idx >> 7) & 127;
        int h = idx & 127;
        Wt[(k << 14) + (h << 7) + f] = f2bf(W[idx]);
        return;
    }
    int idx2 = idx - 114688;
    if (idx2 < 14336) {
        int j = idx2 & 7;
        int lane = (idx2 >> 3) & 63;
        int kk = (idx2 >> 9) & 3;
        int k = idx2 >> 11;
        int c = lane & 15;
        int off = ((lane >> 4) << 3) + j;
        int f = kk * 32 + (off >> 1) + ((off & 1) << 4);
        int ck = (k < 5) ? 3 : 2;
        float s = 0.0f;
        if (c < ck) {
            const float* R = (k < 5) ? (r3w + (size_t)(k * 3 + c) * H)
                                     : (r2w + (size_t)((k - 5) * 2 + c) * H);
            const float* Wk = W + (k << 14) + (f << 7);
            for (int h = 0; h < H; ++h) s += Wk[h] * R[h];
        }
        WRb[idx2] = f2bf(s);
    } else if (idx2 < 14336 + 32) {
        int c32 = idx2 - 14336;
        int k = c32 >> 2, c = c32 & 3;
        int ck = (k < 5) ? 3 : 2;
        float t = 0.0f;
        if (c < ck) {
            const float* R = (k < 5) ? (r3w + (size_t)(k * 3 + c) * H)
                                     : (r2w + (size_t)((k - 5) * 2 + c) * H);
            const float* bk = b + k * H;
            for (int h = 0; h < H; ++h) t += bk[h] * R[h];
            t += (k < 5) ? r3b[k * 3 + c] : r2b[(k - 5) * 2 + c];
        }
        bias2[c32] = t;
    }
}

// ---- aggregation 1: px = P_hat @ x --------------------------------------
__global__ void __launch_bounds__(256) k_px(const unsigned* __restrict__ xb,
        const int* __restrict__ rp, const int* __restrict__ csrc,
        const float* __restrict__ cw, const float* __restrict__ invdeg,
        unsigned* __restrict__ pxb, int N) {
    int lane = threadIdx.x & 63;
    int wv = threadIdx.x >> 6;
    int i = blockIdx.x * 4 + wv;
    if (i >= N) return;
    int grp = lane >> 4, sub = lane & 15;
    const unsigned* xbs = xb + sub * 4;
    int s = rp[i], e = rp[i + 1];
    float acc[8] = {0.f, 0.f, 0.f, 0.f, 0.f, 0.f, 0.f, 0.f};
    float acb[8] = {0.f, 0.f, 0.f, 0.f, 0.f, 0.f, 0.f, 0.f};
    for (int base = s; base < e; base += 64) {
        int el = base + lane;
        bool ok = el < e;
        int j_l = ok ? csrc[el] : 0;
        float w_l = ok ? cw[el] : 0.0f;
        int cnt = e - base; if (cnt > 64) cnt = 64;
        for (int t = 0; t < cnt; t += 8) {
            int i0 = t + grp, i1 = t + 4 + grp;
            int jj0 = __shfl(j_l, i0);   float ww0 = __shfl(w_l, i0);
            int jj1 = __shfl(j_l, i1);   float ww1 = __shfl(w_l, i1);
            const uint4 v0 = *(const uint4*)(xbs + (size_t)jj0 * 64);
            const uint4 v1 = *(const uint4*)(xbs + (size_t)jj1 * 64);
            acc[0] += ww0 * bflo(v0.x); acc[1] += ww0 * bfhi(v0.x);
            acc[2] += ww0 * bflo(v0.y); acc[3] += ww0 * bfhi(v0.y);
            acc[4] += ww0 * bflo(v0.z); acc[5] += ww0 * bfhi(v0.z);
            acc[6] += ww0 * bflo(v0.w); acc[7] += ww0 * bfhi(v0.w);
            acb[0] += ww1 * bflo(v1.x); acb[1] += ww1 * bfhi(v1.x);
            acb[2] += ww1 * bflo(v1.y); acb[3] += ww1 * bfhi(v1.y);
            acb[4] += ww1 * bflo(v1.z); acb[5] += ww1 * bfhi(v1.z);
            acb[6] += ww1 * bflo(v1.w); acb[7] += ww1 * bfhi(v1.w);
        }
    }
#pragma unroll
    for (int r = 0; r < 8; ++r) {
        acc[r] += acb[r];
        acc[r] += __shfl_xor(acc[r], 16);
        acc[r] += __shfl_xor(acc[r], 32);
    }
    if (grp == 0) {
        const uint4 v = *(const uint4*)(xbs + (size_t)i * 64);
        float id = invdeg[i];
        uint4 o;
        o.x = (unsigned)f2bf(acc[0] + id * bflo(v.x)) | ((unsigned)f2bf(acc[1] + id * bfhi(v.x)) << 16);
        o.y = (unsigned)f2bf(acc[2] + id * bflo(v.y)) | ((unsigned)f2bf(acc[3] + id * bfhi(v.y)) << 16);
        o.z = (unsigned)f2bf(acc[4] + id * bflo(v.z)) | ((unsigned)f2bf(acc[5] + id * bfhi(v.z)) << 16);
        o.w = (unsigned)f2bf(acc[6] + id * bflo(v.w)) | ((unsigned)f2bf(acc[7] + id * bfhi(v.w)) << 16);
        *(uint4*)(pxb + (size_t)i * 64 + sub * 4) = o;
    }
}

// ---- GEMM: u = (relu(px@Wk + bk)) @ WR_k --------------------------------
// R6 version: LDS-staged B, fp32 uall writes (16B contiguous per branch/row
// — NO sub-16B scatter: 7 XCD-distributed blocks per row-line must not do
// partial-sector writes, that caused 15x HBM write amplification in R7).
__global__ void __launch_bounds__(256, 2) k_gemm(const unsigned short* __restrict__ pxb,
        const unsigned short* __restrict__ Wt, const float* __restrict__ gb,
        const unsigned short* __restrict__ WRb, float* __restrict__ uall, int N) {
    __shared__ __align__(16) unsigned short Bs[128 * 136];
    __shared__ __align__(16) unsigned h1w[4][2560];
    int k = blockIdx.y;
    int wv = threadIdx.x >> 6;
    int lane = threadIdx.x & 63;
    int quad = lane >> 4, l16 = lane & 15;

    {
        const unsigned short* src = Wt + (k << 14);
        int t = threadIdx.x;
#pragma unroll
        for (int i = 0; i < 8; ++i) {
            int li = i * 256 + t;
            int f = li >> 4, seg = li & 15;
            *(bf16x8*)(Bs + f * 136 + seg * 8) = *(const bf16x8*)(src + f * 128 + seg * 8);
        }
    }
    __syncthreads();

    unsigned* wl = &h1w[wv][0];
    int rowbase = blockIdx.x * 512 + wv * 32;

    bf16x8 af[2][2][4];
    {
        int rb0 = rowbase;
#pragma unroll
        for (int rb = 0; rb < 2; ++rb) {
            int r = rb0 + rb * 16 + l16;
            if (r >= N) r = N - 1;
#pragma unroll
            for (int kk = 0; kk < 4; ++kk)
                af[0][rb][kk] = *(const bf16x8*)(pxb + (size_t)r * H + kk * 32 + quad * 8);
        }
    }

    float bi[4][2];
#pragma unroll
    for (int p = 0; p < 4; ++p) {
        bi[p][0] = gb[k * H + 32 * p + l16];
        bi[p][1] = gb[k * H + 32 * p + 16 + l16];
    }
    bf16x8 bw[4];
#pragma unroll
    for (int kk = 0; kk < 4; ++kk)
        bw[kk] = *(const bf16x8*)(WRb + (size_t)((k * 4 + kk) * 64 + lane) * 8);

    for (int t = 0; t < 4; ++t) {
        if (t < 3) {
            int rb0 = rowbase + (t + 1) * 128;
#pragma unroll
            for (int rb = 0; rb < 2; ++rb) {
                int r = rb0 + rb * 16 + l16;
                if (r >= N) r = N - 1;
#pragma unroll
                for (int kk = 0; kk < 4; ++kk)
                    af[(t + 1) & 1][rb][kk] = *(const bf16x8*)(pxb + (size_t)r * H + kk * 32 + quad * 8);
            }
        }
        int row0 = rowbase + t * 128;
#pragma unroll
        for (int p = 0; p < 4; ++p) {
            f32x4 cacc[2][2] = {};
#pragma unroll
            for (int kk = 0; kk < 4; ++kk) {
                bf16x8 b0 = *(const bf16x8*)(Bs + (32 * p + l16) * 136 + kk * 32 + quad * 8);
                bf16x8 b1 = *(const bf16x8*)(Bs + (32 * p + 16 + l16) * 136 + kk * 32 + quad * 8);
#pragma unroll
                for (int rb = 0; rb < 2; ++rb) {
                    cacc[rb][0] = __builtin_amdgcn_mfma_f32_16x16x32_bf16(af[t & 1][rb][kk], b0, cacc[rb][0], 0, 0, 0);
                    cacc[rb][1] = __builtin_amdgcn_mfma_f32_16x16x32_bf16(af[t & 1][rb][kk], b1, cacc[rb][1], 0, 0, 0);
                }
            }
#pragma unroll
            for (int rb = 0; rb < 2; ++rb)
#pragma unroll
                for (int r = 0; r < 4; ++r) {
                    float lo = fmaxf(cacc[rb][0][r] + bi[p][0], 0.0f);
                    float hi = fmaxf(cacc[rb][1][r] + bi[p][1], 0.0f);
                    unsigned pk = (unsigned)f2bf(lo) | ((unsigned)f2bf(hi) << 16);
                    wl[(p * 32 + rb * 16 + quad * 4 + r) * 20 + l16] = pk;
                }
        }
        // projection GEMM (K=128 permuted), wave-local, no barrier
        f32x4 u0 = {}, u1 = {};
#pragma unroll
        for (int kk = 0; kk < 4; ++kk) {
            bf16x8 a0 = *(const bf16x8*)(wl + (kk * 32 + l16) * 20 + quad * 4);
            bf16x8 a1 = *(const bf16x8*)(wl + (kk * 32 + 16 + l16) * 20 + quad * 4);
            u0 = __builtin_amdgcn_mfma_f32_16x16x32_bf16(a0, bw[kk], u0, 0, 0, 0);
            u1 = __builtin_amdgcn_mfma_f32_16x16x32_bf16(a1, bw[kk], u1, 0, 0, 0);
        }
        if (l16 < 4) {
#pragma unroll
            for (int r = 0; r < 4; ++r) {
                int ra = row0 + quad * 4 + r;
                int rb2 = ra + 16;
                if (ra < N) uall[(size_t)ra * 32 + k * 4 + l16] = u0[r];
                if (rb2 < N) uall[(size_t)rb2 * 32 + k * 4 + l16] = u1[r];
            }
        }
    }
}

// ---- aggregation 2 + softmax (bf16 u, 4 lanes/row, 16 edges/instr) ------
__global__ void __launch_bounds__(256) k_out(const unsigned* __restrict__ uallb,
        const int* __restrict__ rp, const int* __restrict__ csrc,
        const float* __restrict__ cw, const float* __restrict__ invdeg,
        const float* __restrict__ bias2, float* __restrict__ out, int N) {
    int lane = threadIdx.x & 63;
    int wv = threadIdx.x >> 6;
    int i = blockIdx.x * 4 + wv;
    if (i >= N) return;
    int grp = lane >> 2, sub = lane & 3;
    const unsigned* us = uallb + sub * 4;
    int s = rp[i], e = rp[i + 1];
    float acc[8] = {0.f, 0.f, 0.f, 0.f, 0.f, 0.f, 0.f, 0.f};
    for (int base = s; base < e; base += 64) {
        int el = base + lane;
        bool ok = el < e;
        int j_l = ok ? csrc[el] : 0;
        float w_l = ok ? cw[el] : 0.0f;
        int cnt = e - base; if (cnt > 64) cnt = 64;
        for (int t = 0; t < cnt; t += 16) {
            int idx = t + grp;
            int jj = __shfl(j_l, idx);
            float ww = __shfl(w_l, idx);
            const uint4 v = *(const uint4*)(us + (size_t)jj * 16);
            acc[0] += ww * bflo(v.x); acc[1] += ww * bfhi(v.x);
            acc[2] += ww * bflo(v.y); acc[3] += ww * bfhi(v.y);
            acc[4] += ww * bflo(v.z); acc[5] += ww * bfhi(v.z);
            acc[6] += ww * bflo(v.w); acc[7] += ww * bfhi(v.w);
        }
    }
#pragma unroll
    for (int r = 0; r < 8; ++r) {
        acc[r] += __shfl_xor(acc[r], 4);
        acc[r] += __shfl_xor(acc[r], 8);
        acc[r] += __shfl_xor(acc[r], 16);
        acc[r] += __shfl_xor(acc[r], 32);
    }
    if (grp == 0) {   // lanes 0..3; lane sub owns branches 2*sub(, 2*sub+1)
        const uint4 sv = *(const uint4*)(us + (size_t)i * 16);
        float id = invdeg[i];
        float4 bA = *(const float4*)(bias2 + sub * 8);
        float4 bB = *(const float4*)(bias2 + sub * 8 + 4);
        float w0 = acc[0] + id * bflo(sv.x) + bA.x;
        float w1 = acc[1] + id * bfhi(sv.x) + bA.y;
        float w2 = acc[2] + id * bflo(sv.y) + bA.z;
        float w4 = acc[4] + id * bflo(sv.z) + bB.x;
        float w5 = acc[5] + id * bfhi(sv.z) + bB.y;
        float w6 = acc[6] + id * bflo(sv.w) + bB.z;
        auto wr = [&](int b, float v0, float v1, float v2) {
            int ck = (b < 5) ? 3 : 2;
            float mx = fmaxf(v0, v1);
            if (ck == 3) mx = fmaxf(mx, v2);
            float e0 = __expf(v0 - mx), e1 = __expf(v1 - mx);
            float e2 = (ck == 3) ? __expf(v2 - mx) : 0.0f;
            float inv = 1.0f / (e0 + e1 + e2);
            size_t bb = (b < 5) ? (size_t)b * 3 * N + (size_t)i * 3
                                : (size_t)15 * N + (size_t)(b - 5) * 2 * N + (size_t)i * 2;
            out[bb] = e0 * inv;
            out[bb + 1] = e1 * inv;
            if (ck == 3) out[bb + 2] = e2 * inv;
        };
        wr(sub * 2, w0, w1, w2);
        if (sub < 3) wr(sub * 2 + 1, w4, w5, w6);
    }
}

// ---- launch -------------------------------------------------------------
extern "C" void kernel_launch(void* const* d_in, const int* in_sizes, int n_in,
                              void* d_out, int out_size, void* d_ws, size_t ws_size,
                              hipStream_t stream) {
    (void)n_in; (void)out_size; (void)ws_size;
    const float* x   = (const float*)d_in[0];
    const int*   ei  = (const int*)d_in[1];
    const float* gw  = (const float*)d_in[2];
    const float* gb  = (const float*)d_in[3];
    const float* r3w = (const float*)d_in[4];
    const float* r3b = (const float*)d_in[5];
    const float* r2w = (const float*)d_in[6];
    const float* r2b = (const float*)d_in[7];
    float* out = (float*)d_out;
    int N = in_sizes[0] / H;   // 100000
    int E = in_sizes[1] / 2;   // 1600000
    int NB = (N + 255) >> 8;   // 391 buckets

    char* p = (char*)d_ws;
    auto alloc = [&](size_t bytes) {
        char* q = p;
        p += (bytes + 255) & ~(size_t)255;
        return q;
    };
    unsigned*       xb     = (unsigned*)alloc((size_t)N * 64 * 4);
    unsigned*       pxb    = (unsigned*)alloc((size_t)N * 64 * 4);
    unsigned short* Wt     = (unsigned short*)alloc((size_t)7 * 16384 * 2);
    unsigned short* WRb    = (unsigned short*)alloc((size_t)14336 * 2);
    float*          bias2  = (float*)alloc(32 * 4);
    int*            bhist  = (int*)alloc(512 * 4);
    int*            bbase  = (int*)alloc(513 * 4);
    int*            gcur   = (int*)alloc(512 * 4);
    int2*           tmp_sd = (int2*)alloc((size_t)E * 8);
    int*            rp     = (int*)alloc((size_t)(N + 1) * 4);
    float*          dinv   = (float*)alloc((size_t)N * 4);
    float*          invdeg = (float*)alloc((size_t)N * 4);
    int*            csrc   = (int*)alloc((size_t)E * 4);
    float*          cw     = (float*)alloc((size_t)E * 4);
    float*          uall   = (float*)alloc((size_t)N * 32 * 4);      // fp32 [N,32]
    unsigned*       uallb  = (unsigned*)alloc((size_t)N * 16 * 4);   // bf16 [N,32]

    hipMemsetAsync(bhist, 0, 512 * 4, stream);
    k_bhist<<<256, 256, 0, stream>>>(ei, bhist, E);
    k_bscan<<<1, 512, 0, stream>>>(bhist, bbase, gcur);
    k_scatter<<<256, 256, 0, stream>>>(ei, gcur, tmp_sd, E);
    k_csrA<<<NB, 256, 0, stream>>>(tmp_sd, bbase, rp, dinv, invdeg, N, E);
    k_csrB<<<NB, 256, 0, stream>>>(tmp_sd, bbase, rp, dinv, csrc, cw, N);
    k_xbf<<<(N * 64 + 255) / 256, 256, 0, stream>>>(x, xb, N * 64);
    k_wprep<<<(114688 + 14368 + 255) / 256, 256, 0, stream>>>(gw, gb, r3w, r3b, r2w, r2b,
                                                              Wt, WRb, bias2);
    k_px<<<(N + 3) / 4, 256, 0, stream>>>(xb, rp, csrc, cw, invdeg, pxb, N);
    dim3 gg((N + 511) / 512, 7);
    k_gemm<<<gg, 256, 0, stream>>>((const unsigned short*)pxb, Wt, gb, WRb, uall, N);
    k_xbf<<<(N * 16 + 255) / 256, 256, 0, stream>>>(uall, uallb, N * 16);
    k_out<<<(N + 3) / 4, 256, 0, stream>>>(uallb, rp, csrc, cw, invdeg, bias2, out, N);
}

// Round 9
// 322.438 us; speedup vs baseline: 1.3086x; 1.0348x over previous
//
#include <hip/hip_runtime.h>

#define H 128

typedef __attribute__((ext_vector_type(8))) short bf16x8;
typedef __attribute__((ext_vector_type(4))) float f32x4;

__device__ __forceinline__ unsigned short f2bf(float f) {
    unsigned u = __float_as_uint(f);
    u += 0x7FFFu + ((u >> 16) & 1u);
    return (unsigned short)(u >> 16);
}
__device__ __forceinline__ float bflo(unsigned v) { return __uint_as_float(v << 16); }
__device__ __forceinline__ float bfhi(unsigned v) { return __uint_as_float(v & 0xFFFF0000u); }

// ---- CSR build via 2-level bucket sort ----------------------------------
__global__ void __launch_bounds__(256) k_bhist(const int* __restrict__ ei,
                                               int* __restrict__ bhist, int E) {
    __shared__ int h[512];
    int t = threadIdx.x;
    h[t] = 0; h[t + 256] = 0;
    __syncthreads();
    int stride = gridDim.x * 256;
    for (int e = blockIdx.x * 256 + t; e < E; e += stride)
        atomicAdd(&h[ei[E + e] >> 8], 1);
    __syncthreads();
    for (int u = t; u < 512; u += 256) {
        int v = h[u];
        if (v) atomicAdd(&bhist[u], v);
    }
}

__global__ void k_bscan(const int* __restrict__ bhist, int* __restrict__ bbase,
                        int* __restrict__ gcur) {
    __shared__ int sh[512];
    int t = threadIdx.x;
    int v = bhist[t];
    sh[t] = v;
    __syncthreads();
    for (int off = 1; off < 512; off <<= 1) {
        int u = (t >= off) ? sh[t - off] : 0;
        __syncthreads();
        sh[t] += u;
        __syncthreads();
    }
    int ex = sh[t] - v;
    bbase[t] = ex;
    gcur[t] = ex;
    if (t == 511) bbase[512] = sh[t];
}

// scatter packed {src | dst_low8<<24} into bucket regions
__global__ void __launch_bounds__(256) k_scatter(const int* __restrict__ ei,
        int* __restrict__ gcur, int* __restrict__ tmp_e, int E) {
    __shared__ int hist[512], base[512], fill[512];
    int blk = blockIdx.x, t = threadIdx.x;
    int chunk = (E + gridDim.x - 1) / gridDim.x;
    int c0 = blk * chunk;
    int c1 = c0 + chunk; if (c1 > E) c1 = E;
    hist[t] = 0; hist[t + 256] = 0;
    __syncthreads();
    for (int e = c0 + t; e < c1; e += 256)
        atomicAdd(&hist[ei[E + e] >> 8], 1);
    __syncthreads();
    for (int u = t; u < 512; u += 256) {
        int h = hist[u];
        base[u] = h ? atomicAdd(&gcur[u], h) : 0;
        fill[u] = 0;
    }
    __syncthreads();
    for (int e = c0 + t; e < c1; e += 256) {
        int d = ei[E + e], s = ei[e];
        int bb = d >> 8;
        int p = base[bb] + atomicAdd(&fill[bb], 1);
        tmp_e[p] = s | ((d & 255) << 24);
    }
}

// merged per-bucket: count + scan -> rp, dinv; then scatter csrc
__global__ void __launch_bounds__(256) k_csrAB(const int* __restrict__ tmp_e,
        const int* __restrict__ bbase, int* __restrict__ rp,
        float* __restrict__ dinv, int* __restrict__ csrc, int N, int E) {
    __shared__ int cnt[256];
    __shared__ int sh[256];
    __shared__ int fill[256];
    int b = blockIdx.x, t = threadIdx.x;
    int e0 = bbase[b], e1 = bbase[b + 1];
    cnt[t] = 0;
    __syncthreads();
    for (int e = e0 + t; e < e1; e += 256)
        atomicAdd(&cnt[(unsigned)tmp_e[e] >> 24], 1);
    __syncthreads();
    int v = cnt[t];
    sh[t] = v;
    __syncthreads();
    for (int off = 1; off < 256; off <<= 1) {
        int u = (t >= off) ? sh[t - off] : 0;
        __syncthreads();
        sh[t] += u;
        __syncthreads();
    }
    int myrp = e0 + sh[t] - v;
    fill[t] = myrp;
    int gid = (b << 8) + t;
    if (gid < N) {
        rp[gid] = myrp;
        dinv[gid] = rsqrtf((float)(v + 1));
    }
    if (b == 0 && t == 0) rp[N] = E;
    __syncthreads();
    for (int e = e0 + t; e < e1; e += 256) {
        int te = tmp_e[e];
        int l = (unsigned)te >> 24;
        int p = atomicAdd(&fill[l], 1);
        csrc[p] = te & 0xFFFFFF;
    }
}

// ---- prep: xs[j] = bf16(dinv[j] * x[j]); zero row at index N ------------
__global__ void k_xscale(const float* __restrict__ x, const float* __restrict__ dinv,
                         unsigned* __restrict__ xs, int N) {
    int i = blockIdx.x * blockDim.x + threadIdx.x;
    int total = N * 64;
    if (i < total) {
        float d = dinv[i >> 6];
        float2 v = ((const float2*)x)[i];
        xs[i] = (unsigned)f2bf(d * v.x) | ((unsigned)f2bf(d * v.y) << 16);
    } else if (i < total + 64) {
        xs[i] = 0;
    }
}

// ---- prep: us[j] = bf16(dinv[j] * u[j]); zero row at index N ------------
__global__ void k_uscale(const float* __restrict__ u, const float* __restrict__ dinv,
                         unsigned* __restrict__ us, int N) {
    int i = blockIdx.x * blockDim.x + threadIdx.x;
    int total = N * 16;
    if (i < total) {
        float d = dinv[i >> 4];
        float2 v = ((const float2*)u)[i];
        us[i] = (unsigned)f2bf(d * v.x) | ((unsigned)f2bf(d * v.y) << 16);
    } else if (i < total + 16) {
        us[i] = 0;
    }
}

// merged weight prep (unchanged)
__global__ void k_wprep(const float* __restrict__ W, const float* __restrict__ b,
                        const float* __restrict__ r3w, const float* __restrict__ r3b,
                        const float* __restrict__ r2w, const float* __restrict__ r2b,
                        unsigned short* __restrict__ Wt, unsigned short* __restrict__ WRb,
                        float* __restrict__ bias2) {
    int idx = blockIdx.x * blockDim.x + threadIdx.x;
    if (idx < 114688) {
        int k = idx >> 14;
        int f = (idx >> 7) & 127;
        int h = idx & 127;
        Wt[(k << 14) + (h << 7) + f] = f2bf(W[idx]);
        return;
    }
    int idx2 = idx - 114688;
    if (idx2 < 14336) {
        int j = idx2 & 7;
        int lane = (idx2 >> 3) & 63;
        int kk = (idx2 >> 9) & 3;
        int k = idx2 >> 11;
        int c = lane & 15;
        int off = ((lane >> 4) << 3) + j;
        int f = kk * 32 + (off >> 1) + ((off & 1) << 4);
        int ck = (k < 5) ? 3 : 2;
        float s = 0.0f;
        if (c < ck) {
            const float* R = (k < 5) ? (r3w + (size_t)(k * 3 + c) * H)
                                     : (r2w + (size_t)((k - 5) * 2 + c) * H);
            const float* Wk = W + (k << 14) + (f << 7);
            for (int h = 0; h < H; ++h) s += Wk[h] * R[h];
        }
        WRb[idx2] = f2bf(s);
    } else if (idx2 < 14336 + 32) {
        int c32 = idx2 - 14336;
        int k = c32 >> 2, c = c32 & 3;
        int ck = (k < 5) ? 3 : 2;
        float t = 0.0f;
        if (c < ck) {
            const float* R = (k < 5) ? (r3w + (size_t)(k * 3 + c) * H)
                                     : (r2w + (size_t)((k - 5) * 2 + c) * H);
            const float* bk = b + k * H;
            for (int h = 0; h < H; ++h) t += bk[h] * R[h];
            t += (k < 5) ? r3b[k * 3 + c] : r2b[(k - 5) * 2 + c];
        }
        bias2[c32] = t;
    }
}

// ---- aggregation 1: px[i] = dinv[i] * (sum_j xs[j] + xs[i]) -------------
// wave/node; 16 lanes x 16B = one row; invalid lanes -> zero row N
__global__ void __launch_bounds__(256) k_px(const unsigned* __restrict__ xs,
        const int* __restrict__ rp, const int* __restrict__ csrc,
        const float* __restrict__ dinv, unsigned* __restrict__ pxb, int N) {
    int lane = threadIdx.x & 63;
    int wv = threadIdx.x >> 6;
    int i = blockIdx.x * 4 + wv;
    if (i >= N) return;
    int grp = lane >> 4, sub = lane & 15;
    const unsigned* xbs = xs + sub * 4;
    int s = rp[i], e = rp[i + 1];
    float acc[8] = {0.f, 0.f, 0.f, 0.f, 0.f, 0.f, 0.f, 0.f};
    float acb[8] = {0.f, 0.f, 0.f, 0.f, 0.f, 0.f, 0.f, 0.f};
    for (int base = s; base < e; base += 64) {
        int el = base + lane;
        int j_l = (el < e) ? csrc[el] : N;
        int cnt = e - base; if (cnt > 64) cnt = 64;
        for (int t = 0; t < cnt; t += 8) {
            int i0 = t + grp, i1 = t + 4 + grp;
            int jj0 = __shfl(j_l, i0);
            int jj1 = __shfl(j_l, i1);
            const uint4 v0 = *(const uint4*)(xbs + (size_t)jj0 * 64);
            const uint4 v1 = *(const uint4*)(xbs + (size_t)jj1 * 64);
            acc[0] += bflo(v0.x); acc[1] += bfhi(v0.x);
            acc[2] += bflo(v0.y); acc[3] += bfhi(v0.y);
            acc[4] += bflo(v0.z); acc[5] += bfhi(v0.z);
            acc[6] += bflo(v0.w); acc[7] += bfhi(v0.w);
            acb[0] += bflo(v1.x); acb[1] += bfhi(v1.x);
            acb[2] += bflo(v1.y); acb[3] += bfhi(v1.y);
            acb[4] += bflo(v1.z); acb[5] += bfhi(v1.z);
            acb[6] += bflo(v1.w); acb[7] += bfhi(v1.w);
        }
    }
#pragma unroll
    for (int r = 0; r < 8; ++r) {
        acc[r] += acb[r];
        acc[r] += __shfl_xor(acc[r], 16);
        acc[r] += __shfl_xor(acc[r], 32);
    }
    if (grp == 0) {
        const uint4 v = *(const uint4*)(xbs + (size_t)i * 64);
        float d = dinv[i];
        uint4 o;
        o.x = (unsigned)f2bf(d * (acc[0] + bflo(v.x))) | ((unsigned)f2bf(d * (acc[1] + bfhi(v.x))) << 16);
        o.y = (unsigned)f2bf(d * (acc[2] + bflo(v.y))) | ((unsigned)f2bf(d * (acc[3] + bfhi(v.y))) << 16);
        o.z = (unsigned)f2bf(d * (acc[4] + bflo(v.z))) | ((unsigned)f2bf(d * (acc[5] + bfhi(v.z))) << 16);
        o.w = (unsigned)f2bf(d * (acc[6] + bflo(v.w))) | ((unsigned)f2bf(d * (acc[7] + bfhi(v.w))) << 16);
        *(uint4*)(pxb + (size_t)i * 64 + sub * 4) = o;
    }
}

// ---- GEMM: u = (relu(px@Wk + bk)) @ WR_k (unchanged R6/R8 core) ---------
__global__ void __launch_bounds__(256, 2) k_gemm(const unsigned short* __restrict__ pxb,
        const unsigned short* __restrict__ Wt, const float* __restrict__ gb,
        const unsigned short* __restrict__ WRb, float* __restrict__ uall, int N) {
    __shared__ __align__(16) unsigned short Bs[128 * 136];
    __shared__ __align__(16) unsigned h1w[4][2560];
    int k = blockIdx.y;
    int wv = threadIdx.x >> 6;
    int lane = threadIdx.x & 63;
    int quad = lane >> 4, l16 = lane & 15;

    {
        const unsigned short* src = Wt + (k << 14);
        int t = threadIdx.x;
#pragma unroll
        for (int i = 0; i < 8; ++i) {
            int li = i * 256 + t;
            int f = li >> 4, seg = li & 15;
            *(bf16x8*)(Bs + f * 136 + seg * 8) = *(const bf16x8*)(src + f * 128 + seg * 8);
        }
    }
    __syncthreads();

    unsigned* wl = &h1w[wv][0];
    int rowbase = blockIdx.x * 512 + wv * 32;

    bf16x8 af[2][2][4];
    {
        int rb0 = rowbase;
#pragma unroll
        for (int rb = 0; rb < 2; ++rb) {
            int r = rb0 + rb * 16 + l16;
            if (r >= N) r = N - 1;
#pragma unroll
            for (int kk = 0; kk < 4; ++kk)
                af[0][rb][kk] = *(const bf16x8*)(pxb + (size_t)r * H + kk * 32 + quad * 8);
        }
    }

    float bi[4][2];
#pragma unroll
    for (int p = 0; p < 4; ++p) {
        bi[p][0] = gb[k * H + 32 * p + l16];
        bi[p][1] = gb[k * H + 32 * p + 16 + l16];
    }
    bf16x8 bw[4];
#pragma unroll
    for (int kk = 0; kk < 4; ++kk)
        bw[kk] = *(const bf16x8*)(WRb + (size_t)((k * 4 + kk) * 64 + lane) * 8);

    for (int t = 0; t < 4; ++t) {
        if (t < 3) {
            int rb0 = rowbase + (t + 1) * 128;
#pragma unroll
            for (int rb = 0; rb < 2; ++rb) {
                int r = rb0 + rb * 16 + l16;
                if (r >= N) r = N - 1;
#pragma unroll
                for (int kk = 0; kk < 4; ++kk)
                    af[(t + 1) & 1][rb][kk] = *(const bf16x8*)(pxb + (size_t)r * H + kk * 32 + quad * 8);
            }
        }
        int row0 = rowbase + t * 128;
#pragma unroll
        for (int p = 0; p < 4; ++p) {
            f32x4 cacc[2][2] = {};
#pragma unroll
            for (int kk = 0; kk < 4; ++kk) {
                bf16x8 b0 = *(const bf16x8*)(Bs + (32 * p + l16) * 136 + kk * 32 + quad * 8);
                bf16x8 b1 = *(const bf16x8*)(Bs + (32 * p + 16 + l16) * 136 + kk * 32 + quad * 8);
#pragma unroll
                for (int rb = 0; rb < 2; ++rb) {
                    cacc[rb][0] = __builtin_amdgcn_mfma_f32_16x16x32_bf16(af[t & 1][rb][kk], b0, cacc[rb][0], 0, 0, 0);
                    cacc[rb][1] = __builtin_amdgcn_mfma_f32_16x16x32_bf16(af[t & 1][rb][kk], b1, cacc[rb][1], 0, 0, 0);
                }
            }
#pragma unroll
            for (int rb = 0; rb < 2; ++rb)
#pragma unroll
                for (int r = 0; r < 4; ++r) {
                    float lo = fmaxf(cacc[rb][0][r] + bi[p][0], 0.0f);
                    float hi = fmaxf(cacc[rb][1][r] + bi[p][1], 0.0f);
                    unsigned pk = (unsigned)f2bf(lo) | ((unsigned)f2bf(hi) << 16);
                    wl[(p * 32 + rb * 16 + quad * 4 + r) * 20 + l16] = pk;
                }
        }
        f32x4 u0 = {}, u1 = {};
#pragma unroll
        for (int kk = 0; kk < 4; ++kk) {
            bf16x8 a0 = *(const bf16x8*)(wl + (kk * 32 + l16) * 20 + quad * 4);
            bf16x8 a1 = *(const bf16x8*)(wl + (kk * 32 + 16 + l16) * 20 + quad * 4);
            u0 = __builtin_amdgcn_mfma_f32_16x16x32_bf16(a0, bw[kk], u0, 0, 0, 0);
            u1 = __builtin_amdgcn_mfma_f32_16x16x32_bf16(a1, bw[kk], u1, 0, 0, 0);
        }
        if (l16 < 4) {
#pragma unroll
            for (int r = 0; r < 4; ++r) {
                int ra = row0 + quad * 4 + r;
                int rb2 = ra + 16;
                if (ra < N) uall[(size_t)ra * 32 + k * 4 + l16] = u0[r];
                if (rb2 < N) uall[(size_t)rb2 * 32 + k * 4 + l16] = u1[r];
            }
        }
    }
}

// ---- aggregation 2 + softmax: v = dinv[i]*(sum us[j] + us[i]) + bias ----
__global__ void __launch_bounds__(256) k_out(const unsigned* __restrict__ us,
        const int* __restrict__ rp, const int* __restrict__ csrc,
        const float* __restrict__ dinv, const float* __restrict__ bias2,
        float* __restrict__ out, int N) {
    int lane = threadIdx.x & 63;
    int wv = threadIdx.x >> 6;
    int i = blockIdx.x * 4 + wv;
    if (i >= N) return;
    int grp = lane >> 2, sub = lane & 3;
    const unsigned* usb = us + sub * 4;
    int s = rp[i], e = rp[i + 1];
    float acc[8] = {0.f, 0.f, 0.f, 0.f, 0.f, 0.f, 0.f, 0.f};
    for (int base = s; base < e; base += 64) {
        int el = base + lane;
        int j_l = (el < e) ? csrc[el] : N;
        int cnt = e - base; if (cnt > 64) cnt = 64;
        for (int t = 0; t < cnt; t += 16) {
            int idx = t + grp;
            int jj = __shfl(j_l, idx);
            const uint4 v = *(const uint4*)(usb + (size_t)jj * 16);
            acc[0] += bflo(v.x); acc[1] += bfhi(v.x);
            acc[2] += bflo(v.y); acc[3] += bfhi(v.y);
            acc[4] += bflo(v.z); acc[5] += bfhi(v.z);
            acc[6] += bflo(v.w); acc[7] += bfhi(v.w);
        }
    }
#pragma unroll
    for (int r = 0; r < 8; ++r) {
        acc[r] += __shfl_xor(acc[r], 4);
        acc[r] += __shfl_xor(acc[r], 8);
        acc[r] += __shfl_xor(acc[r], 16);
        acc[r] += __shfl_xor(acc[r], 32);
    }
    if (grp == 0) {   // lanes 0..3; lane sub owns branches 2*sub(, 2*sub+1)
        const uint4 sv = *(const uint4*)(usb + (size_t)i * 16);
        float d = dinv[i];
        float4 bA = *(const float4*)(bias2 + sub * 8);
        float4 bB = *(const float4*)(bias2 + sub * 8 + 4);
        float w0 = d * (acc[0] + bflo(sv.x)) + bA.x;
        float w1 = d * (acc[1] + bfhi(sv.x)) + bA.y;
        float w2 = d * (acc[2] + bflo(sv.y)) + bA.z;
        float w4 = d * (acc[4] + bflo(sv.z)) + bB.x;
        float w5 = d * (acc[5] + bfhi(sv.z)) + bB.y;
        float w6 = d * (acc[6] + bflo(sv.w)) + bB.z;
        auto wr = [&](int b, float v0, float v1, float v2) {
            int ck = (b < 5) ? 3 : 2;
            float mx = fmaxf(v0, v1);
            if (ck == 3) mx = fmaxf(mx, v2);
            float e0 = __expf(v0 - mx), e1 = __expf(v1 - mx);
            float e2 = (ck == 3) ? __expf(v2 - mx) : 0.0f;
            float inv = 1.0f / (e0 + e1 + e2);
            size_t bb = (b < 5) ? (size_t)b * 3 * N + (size_t)i * 3
                                : (size_t)15 * N + (size_t)(b - 5) * 2 * N + (size_t)i * 2;
            out[bb] = e0 * inv;
            out[bb + 1] = e1 * inv;
            if (ck == 3) out[bb + 2] = e2 * inv;
        };
        wr(sub * 2, w0, w1, w2);
        if (sub < 3) wr(sub * 2 + 1, w4, w5, w6);
    }
}

// ---- launch -------------------------------------------------------------
extern "C" void kernel_launch(void* const* d_in, const int* in_sizes, int n_in,
                              void* d_out, int out_size, void* d_ws, size_t ws_size,
                              hipStream_t stream) {
    (void)n_in; (void)out_size; (void)ws_size;
    const float* x   = (const float*)d_in[0];
    const int*   ei  = (const int*)d_in[1];
    const float* gw  = (const float*)d_in[2];
    const float* gb  = (const float*)d_in[3];
    const float* r3w = (const float*)d_in[4];
    const float* r3b = (const float*)d_in[5];
    const float* r2w = (const float*)d_in[6];
    const float* r2b = (const float*)d_in[7];
    float* out = (float*)d_out;
    int N = in_sizes[0] / H;   // 100000
    int E = in_sizes[1] / 2;   // 1600000
    int NB = (N + 255) >> 8;   // 391 buckets

    char* p = (char*)d_ws;
    auto alloc = [&](size_t bytes) {
        char* q = p;
        p += (bytes + 255) & ~(size_t)255;
        return q;
    };
    unsigned*       xs     = (unsigned*)alloc((size_t)(N + 1) * 64 * 4);  // scaled x bf16, +zero row
    unsigned*       pxb    = (unsigned*)alloc((size_t)N * 64 * 4);
    unsigned short* Wt     = (unsigned short*)alloc((size_t)7 * 16384 * 2);
    unsigned short* WRb    = (unsigned short*)alloc((size_t)14336 * 2);
    float*          bias2  = (float*)alloc(32 * 4);
    int*            bhist  = (int*)alloc(512 * 4);
    int*            bbase  = (int*)alloc(513 * 4);
    int*            gcur   = (int*)alloc(512 * 4);
    int*            tmp_e  = (int*)alloc((size_t)E * 4);
    int*            rp     = (int*)alloc((size_t)(N + 1) * 4);
    float*          dinv   = (float*)alloc((size_t)N * 4);
    int*            csrc   = (int*)alloc((size_t)E * 4);
    float*          uall   = (float*)alloc((size_t)N * 32 * 4);           // fp32 [N,32]
    unsigned*       usb    = (unsigned*)alloc((size_t)(N + 1) * 16 * 4);  // scaled u bf16, +zero row

    hipMemsetAsync(bhist, 0, 512 * 4, stream);
    k_bhist<<<256, 256, 0, stream>>>(ei, bhist, E);
    k_bscan<<<1, 512, 0, stream>>>(bhist, bbase, gcur);
    k_scatter<<<256, 256, 0, stream>>>(ei, gcur, tmp_e, E);
    k_csrAB<<<NB, 256, 0, stream>>>(tmp_e, bbase, rp, dinv, csrc, N, E);
    k_xscale<<<(N * 64 + 64 + 255) / 256, 256, 0, stream>>>(x, dinv, xs, N);
    k_wprep<<<(114688 + 14368 + 255) / 256, 256, 0, stream>>>(gw, gb, r3w, r3b, r2w, r2b,
                                                              Wt, WRb, bias2);
    k_px<<<(N + 3) / 4, 256, 0, stream>>>(xs, rp, csrc, dinv, pxb, N);
    dim3 gg((N + 511) / 512, 7);
    k_gemm<<<gg, 256, 0, stream>>>((const unsigned short*)pxb, Wt, gb, WRb, uall, N);
    k_uscale<<<(N * 16 + 16 + 255) / 256, 256, 0, stream>>>(uall, dinv, usb, N);
    k_out<<<(N + 3) / 4, 256, 0, stream>>>(usb, rp, csrc, dinv, bias2, out, N);
}

// Round 10
// 311.015 us; speedup vs baseline: 1.3567x; 1.0367x over previous
//
#include <hip/hip_runtime.h>

#define H 128

typedef __attribute__((ext_vector_type(8))) short bf16x8;
typedef __attribute__((ext_vector_type(4))) float f32x4;

__device__ __forceinline__ unsigned short f2bf(float f) {
    unsigned u = __float_as_uint(f);
    u += 0x7FFFu + ((u >> 16) & 1u);
    return (unsigned short)(u >> 16);
}
__device__ __forceinline__ float bflo(unsigned v) { return __uint_as_float(v << 16); }
__device__ __forceinline__ float bfhi(unsigned v) { return __uint_as_float(v & 0xFFFF0000u); }

// ---- CSR build via 2-level bucket sort ----------------------------------
__global__ void __launch_bounds__(256) k_bhist(const int* __restrict__ ei,
                                               int* __restrict__ bhist, int E) {
    __shared__ int h[512];
    int t = threadIdx.x;
    h[t] = 0; h[t + 256] = 0;
    __syncthreads();
    int stride = gridDim.x * 256;
    for (int e = blockIdx.x * 256 + t; e < E; e += stride)
        atomicAdd(&h[ei[E + e] >> 8], 1);
    __syncthreads();
    for (int u = t; u < 512; u += 256) {
        int v = h[u];
        if (v) atomicAdd(&bhist[u], v);
    }
}

__global__ void k_bscan(const int* __restrict__ bhist, int* __restrict__ bbase,
                        int* __restrict__ gcur) {
    __shared__ int sh[512];
    int t = threadIdx.x;
    int v = bhist[t];
    sh[t] = v;
    __syncthreads();
    for (int off = 1; off < 512; off <<= 1) {
        int u = (t >= off) ? sh[t - off] : 0;
        __syncthreads();
        sh[t] += u;
        __syncthreads();
    }
    int ex = sh[t] - v;
    bbase[t] = ex;
    gcur[t] = ex;
    if (t == 511) bbase[512] = sh[t];
}

// scatter packed {src | dst_low8<<24} into bucket regions
__global__ void __launch_bounds__(256) k_scatter(const int* __restrict__ ei,
        int* __restrict__ gcur, int* __restrict__ tmp_e, int E) {
    __shared__ int hist[512], base[512], fill[512];
    int blk = blockIdx.x, t = threadIdx.x;
    int chunk = (E + gridDim.x - 1) / gridDim.x;
    int c0 = blk * chunk;
    int c1 = c0 + chunk; if (c1 > E) c1 = E;
    hist[t] = 0; hist[t + 256] = 0;
    __syncthreads();
    for (int e = c0 + t; e < c1; e += 256)
        atomicAdd(&hist[ei[E + e] >> 8], 1);
    __syncthreads();
    for (int u = t; u < 512; u += 256) {
        int h = hist[u];
        base[u] = h ? atomicAdd(&gcur[u], h) : 0;
        fill[u] = 0;
    }
    __syncthreads();
    for (int e = c0 + t; e < c1; e += 256) {
        int d = ei[E + e], s = ei[e];
        int bb = d >> 8;
        int p = base[bb] + atomicAdd(&fill[bb], 1);
        tmp_e[p] = s | ((d & 255) << 24);
    }
}

// merged per-bucket: count + scan -> rp, dinv; then scatter csrc
__global__ void __launch_bounds__(256) k_csrAB(const int* __restrict__ tmp_e,
        const int* __restrict__ bbase, int* __restrict__ rp,
        float* __restrict__ dinv, int* __restrict__ csrc, int N, int E) {
    __shared__ int cnt[256];
    __shared__ int sh[256];
    __shared__ int fill[256];
    int b = blockIdx.x, t = threadIdx.x;
    int e0 = bbase[b], e1 = bbase[b + 1];
    cnt[t] = 0;
    __syncthreads();
    for (int e = e0 + t; e < e1; e += 256)
        atomicAdd(&cnt[(unsigned)tmp_e[e] >> 24], 1);
    __syncthreads();
    int v = cnt[t];
    sh[t] = v;
    __syncthreads();
    for (int off = 1; off < 256; off <<= 1) {
        int u = (t >= off) ? sh[t - off] : 0;
        __syncthreads();
        sh[t] += u;
        __syncthreads();
    }
    int myrp = e0 + sh[t] - v;
    fill[t] = myrp;
    int gid = (b << 8) + t;
    if (gid < N) {
        rp[gid] = myrp;
        dinv[gid] = rsqrtf((float)(v + 1));
    }
    if (b == 0 && t == 0) rp[N] = E;
    __syncthreads();
    for (int e = e0 + t; e < e1; e += 256) {
        int te = tmp_e[e];
        int l = (unsigned)te >> 24;
        int p = atomicAdd(&fill[l], 1);
        csrc[p] = te & 0xFFFFFF;
    }
}

// ---- merged prep: xs scale (+zero row) AND weight prep ------------------
__global__ void k_prep(const float* __restrict__ x, const float* __restrict__ dinv,
                       unsigned* __restrict__ xs, int N,
                       const float* __restrict__ W, const float* __restrict__ b,
                       const float* __restrict__ r3w, const float* __restrict__ r3b,
                       const float* __restrict__ r2w, const float* __restrict__ r2b,
                       unsigned short* __restrict__ Wt, unsigned short* __restrict__ WRb,
                       float* __restrict__ bias2) {
    int gi = blockIdx.x * blockDim.x + threadIdx.x;
    int total = N * 64;
    if (gi < total) {
        float d = dinv[gi >> 6];
        float2 v = ((const float2*)x)[gi];
        xs[gi] = (unsigned)f2bf(d * v.x) | ((unsigned)f2bf(d * v.y) << 16);
        return;
    }
    if (gi < total + 64) { xs[gi] = 0; return; }
    int idx = gi - (total + 64);
    if (idx < 114688) {
        int k = idx >> 14;
        int f = (idx >> 7) & 127;
        int h = idx & 127;
        Wt[(k << 14) + (h << 7) + f] = f2bf(W[idx]);
        return;
    }
    int idx2 = idx - 114688;
    if (idx2 < 14336) {
        int j = idx2 & 7;
        int lane = (idx2 >> 3) & 63;
        int kk = (idx2 >> 9) & 3;
        int k = idx2 >> 11;
        int c = lane & 15;
        int off = ((lane >> 4) << 3) + j;
        int f = kk * 32 + (off >> 1) + ((off & 1) << 4);
        int ck = (k < 5) ? 3 : 2;
        float s = 0.0f;
        if (c < ck) {
            const float* R = (k < 5) ? (r3w + (size_t)(k * 3 + c) * H)
                                     : (r2w + (size_t)((k - 5) * 2 + c) * H);
            const float* Wk = W + (k << 14) + (f << 7);
            for (int h = 0; h < H; ++h) s += Wk[h] * R[h];
        }
        WRb[idx2] = f2bf(s);
    } else if (idx2 < 14336 + 32) {
        int c32 = idx2 - 14336;
        int k = c32 >> 2, c = c32 & 3;
        int ck = (k < 5) ? 3 : 2;
        float t = 0.0f;
        if (c < ck) {
            const float* R = (k < 5) ? (r3w + (size_t)(k * 3 + c) * H)
                                     : (r2w + (size_t)((k - 5) * 2 + c) * H);
            const float* bk = b + k * H;
            for (int h = 0; h < H; ++h) t += bk[h] * R[h];
            t += (k < 5) ? r3b[k * 3 + c] : r2b[(k - 5) * 2 + c];
        }
        bias2[c32] = t;
    }
}

// ---- prep: us[j] = bf16(dinv[j] * u[j]); zero row at index N ------------
__global__ void k_uscale(const float* __restrict__ u, const float* __restrict__ dinv,
                         unsigned* __restrict__ us, int N) {
    int i = blockIdx.x * blockDim.x + threadIdx.x;
    int total = N * 16;
    if (i < total) {
        float d = dinv[i >> 4];
        float2 v = ((const float2*)u)[i];
        us[i] = (unsigned)f2bf(d * v.x) | ((unsigned)f2bf(d * v.y) << 16);
    } else if (i < total + 16) {
        us[i] = 0;
    }
}

__device__ __forceinline__ void acc8(float2* a, const uint4 v) {
    a[0].x += bflo(v.x); a[0].y += bfhi(v.x);
    a[1].x += bflo(v.y); a[1].y += bfhi(v.y);
    a[2].x += bflo(v.z); a[2].y += bfhi(v.z);
    a[3].x += bflo(v.w); a[3].y += bfhi(v.w);
}

// ---- aggregation 1: px[i] = dinv[i] * (sum_j xs[j] + xs[i]) -------------
// wave/node; 16 lanes x 16B = one row; 4 gathers in flight per lane
__global__ void __launch_bounds__(256) k_px(const unsigned* __restrict__ xs,
        const int* __restrict__ rp, const int* __restrict__ csrc,
        const float* __restrict__ dinv, unsigned* __restrict__ pxb, int N) {
    int lane = threadIdx.x & 63;
    int wv = threadIdx.x >> 6;
    int i = blockIdx.x * 4 + wv;
    if (i >= N) return;
    int grp = lane >> 4, sub = lane & 15;
    const unsigned* xbs = xs + sub * 4;
    int s = rp[i], e = rp[i + 1];
    float2 a0[4] = {{0.f,0.f},{0.f,0.f},{0.f,0.f},{0.f,0.f}};
    float2 a1[4] = {{0.f,0.f},{0.f,0.f},{0.f,0.f},{0.f,0.f}};
    for (int base = s; base < e; base += 64) {
        int el = base + lane;
        int j_l = (el < e) ? csrc[el] : N;
        int cnt = e - base; if (cnt > 64) cnt = 64;
        for (int t = 0; t < cnt; t += 16) {
            int jj0 = __shfl(j_l, t + grp);
            int jj1 = __shfl(j_l, t + 4 + grp);
            int jj2 = __shfl(j_l, t + 8 + grp);
            int jj3 = __shfl(j_l, t + 12 + grp);
            const uint4 v0 = *(const uint4*)(xbs + (size_t)jj0 * 64);
            const uint4 v1 = *(const uint4*)(xbs + (size_t)jj1 * 64);
            const uint4 v2 = *(const uint4*)(xbs + (size_t)jj2 * 64);
            const uint4 v3 = *(const uint4*)(xbs + (size_t)jj3 * 64);
            acc8(a0, v0); acc8(a1, v1); acc8(a0, v2); acc8(a1, v3);
        }
    }
    float acc[8];
#pragma unroll
    for (int r = 0; r < 4; ++r) {
        acc[2 * r] = a0[r].x + a1[r].x;
        acc[2 * r + 1] = a0[r].y + a1[r].y;
    }
#pragma unroll
    for (int r = 0; r < 8; ++r) {
        acc[r] += __shfl_xor(acc[r], 16);
        acc[r] += __shfl_xor(acc[r], 32);
    }
    if (grp == 0) {
        const uint4 v = *(const uint4*)(xbs + (size_t)i * 64);
        float d = dinv[i];
        uint4 o;
        o.x = (unsigned)f2bf(d * (acc[0] + bflo(v.x))) | ((unsigned)f2bf(d * (acc[1] + bfhi(v.x))) << 16);
        o.y = (unsigned)f2bf(d * (acc[2] + bflo(v.y))) | ((unsigned)f2bf(d * (acc[3] + bfhi(v.y))) << 16);
        o.z = (unsigned)f2bf(d * (acc[4] + bflo(v.z))) | ((unsigned)f2bf(d * (acc[5] + bfhi(v.z))) << 16);
        o.w = (unsigned)f2bf(d * (acc[6] + bflo(v.w))) | ((unsigned)f2bf(d * (acc[7] + bfhi(v.w))) << 16);
        *(uint4*)(pxb + (size_t)i * 64 + sub * 4) = o;
    }
}

// ---- GEMM: u = (relu(px@Wk + bk)) @ WR_k (unchanged core) ---------------
__global__ void __launch_bounds__(256, 2) k_gemm(const unsigned short* __restrict__ pxb,
        const unsigned short* __restrict__ Wt, const float* __restrict__ gb,
        const unsigned short* __restrict__ WRb, float* __restrict__ uall, int N) {
    __shared__ __align__(16) unsigned short Bs[128 * 136];
    __shared__ __align__(16) unsigned h1w[4][2560];
    int k = blockIdx.y;
    int wv = threadIdx.x >> 6;
    int lane = threadIdx.x & 63;
    int quad = lane >> 4, l16 = lane & 15;

    {
        const unsigned short* src = Wt + (k << 14);
        int t = threadIdx.x;
#pragma unroll
        for (int i = 0; i < 8; ++i) {
            int li = i * 256 + t;
            int f = li >> 4, seg = li & 15;
            *(bf16x8*)(Bs + f * 136 + seg * 8) = *(const bf16x8*)(src + f * 128 + seg * 8);
        }
    }
    __syncthreads();

    unsigned* wl = &h1w[wv][0];
    int rowbase = blockIdx.x * 512 + wv * 32;

    bf16x8 af[2][2][4];
    {
        int rb0 = rowbase;
#pragma unroll
        for (int rb = 0; rb < 2; ++rb) {
            int r = rb0 + rb * 16 + l16;
            if (r >= N) r = N - 1;
#pragma unroll
            for (int kk = 0; kk < 4; ++kk)
                af[0][rb][kk] = *(const bf16x8*)(pxb + (size_t)r * H + kk * 32 + quad * 8);
        }
    }

    float bi[4][2];
#pragma unroll
    for (int p = 0; p < 4; ++p) {
        bi[p][0] = gb[k * H + 32 * p + l16];
        bi[p][1] = gb[k * H + 32 * p + 16 + l16];
    }
    bf16x8 bw[4];
#pragma unroll
    for (int kk = 0; kk < 4; ++kk)
        bw[kk] = *(const bf16x8*)(WRb + (size_t)((k * 4 + kk) * 64 + lane) * 8);

    for (int t = 0; t < 4; ++t) {
        if (t < 3) {
            int rb0 = rowbase + (t + 1) * 128;
#pragma unroll
            for (int rb = 0; rb < 2; ++rb) {
                int r = rb0 + rb * 16 + l16;
                if (r >= N) r = N - 1;
#pragma unroll
                for (int kk = 0; kk < 4; ++kk)
                    af[(t + 1) & 1][rb][kk] = *(const bf16x8*)(pxb + (size_t)r * H + kk * 32 + quad * 8);
            }
        }
        int row0 = rowbase + t * 128;
#pragma unroll
        for (int p = 0; p < 4; ++p) {
            f32x4 cacc[2][2] = {};
#pragma unroll
            for (int kk = 0; kk < 4; ++kk) {
                bf16x8 b0 = *(const bf16x8*)(Bs + (32 * p + l16) * 136 + kk * 32 + quad * 8);
                bf16x8 b1 = *(const bf16x8*)(Bs + (32 * p + 16 + l16) * 136 + kk * 32 + quad * 8);
#pragma unroll
                for (int rb = 0; rb < 2; ++rb) {
                    cacc[rb][0] = __builtin_amdgcn_mfma_f32_16x16x32_bf16(af[t & 1][rb][kk], b0, cacc[rb][0], 0, 0, 0);
                    cacc[rb][1] = __builtin_amdgcn_mfma_f32_16x16x32_bf16(af[t & 1][rb][kk], b1, cacc[rb][1], 0, 0, 0);
                }
            }
#pragma unroll
            for (int rb = 0; rb < 2; ++rb)
#pragma unroll
                for (int r = 0; r < 4; ++r) {
                    float lo = fmaxf(cacc[rb][0][r] + bi[p][0], 0.0f);
                    float hi = fmaxf(cacc[rb][1][r] + bi[p][1], 0.0f);
                    unsigned pk = (unsigned)f2bf(lo) | ((unsigned)f2bf(hi) << 16);
                    wl[(p * 32 + rb * 16 + quad * 4 + r) * 20 + l16] = pk;
                }
        }
        f32x4 u0 = {}, u1 = {};
#pragma unroll
        for (int kk = 0; kk < 4; ++kk) {
            bf16x8 a0 = *(const bf16x8*)(wl + (kk * 32 + l16) * 20 + quad * 4);
            bf16x8 a1 = *(const bf16x8*)(wl + (kk * 32 + 16 + l16) * 20 + quad * 4);
            u0 = __builtin_amdgcn_mfma_f32_16x16x32_bf16(a0, bw[kk], u0, 0, 0, 0);
            u1 = __builtin_amdgcn_mfma_f32_16x16x32_bf16(a1, bw[kk], u1, 0, 0, 0);
        }
        if (l16 < 4) {
#pragma unroll
            for (int r = 0; r < 4; ++r) {
                int ra = row0 + quad * 4 + r;
                int rb2 = ra + 16;
                if (ra < N) uall[(size_t)ra * 32 + k * 4 + l16] = u0[r];
                if (rb2 < N) uall[(size_t)rb2 * 32 + k * 4 + l16] = u1[r];
            }
        }
    }
}

// ---- aggregation 2 + softmax: v = dinv[i]*(sum us[j] + us[i]) + bias ----
__global__ void __launch_bounds__(256) k_out(const unsigned* __restrict__ us,
        const int* __restrict__ rp, const int* __restrict__ csrc,
        const float* __restrict__ dinv, const float* __restrict__ bias2,
        float* __restrict__ out, int N) {
    int lane = threadIdx.x & 63;
    int wv = threadIdx.x >> 6;
    int i = blockIdx.x * 4 + wv;
    if (i >= N) return;
    int grp = lane >> 2, sub = lane & 3;
    const unsigned* usb = us + sub * 4;
    int s = rp[i], e = rp[i + 1];
    float2 a0[4] = {{0.f,0.f},{0.f,0.f},{0.f,0.f},{0.f,0.f}};
    float2 a1[4] = {{0.f,0.f},{0.f,0.f},{0.f,0.f},{0.f,0.f}};
    for (int base = s; base < e; base += 64) {
        int el = base + lane;
        int j_l = (el < e) ? csrc[el] : N;
        int cnt = e - base; if (cnt > 64) cnt = 64;
        for (int t = 0; t < cnt; t += 32) {
            int jj0 = __shfl(j_l, t + grp);
            int jj1 = __shfl(j_l, t + 16 + grp);
            const uint4 v0 = *(const uint4*)(usb + (size_t)jj0 * 16);
            const uint4 v1 = *(const uint4*)(usb + (size_t)jj1 * 16);
            acc8(a0, v0); acc8(a1, v1);
        }
    }
    float acc[8];
#pragma unroll
    for (int r = 0; r < 4; ++r) {
        acc[2 * r] = a0[r].x + a1[r].x;
        acc[2 * r + 1] = a0[r].y + a1[r].y;
    }
#pragma unroll
    for (int r = 0; r < 8; ++r) {
        acc[r] += __shfl_xor(acc[r], 4);
        acc[r] += __shfl_xor(acc[r], 8);
        acc[r] += __shfl_xor(acc[r], 16);
        acc[r] += __shfl_xor(acc[r], 32);
    }
    if (grp == 0) {   // lanes 0..3; lane sub owns branches 2*sub(, 2*sub+1)
        const uint4 sv = *(const uint4*)(usb + (size_t)i * 16);
        float d = dinv[i];
        float4 bA = *(const float4*)(bias2 + sub * 8);
        float4 bB = *(const float4*)(bias2 + sub * 8 + 4);
        float w0 = d * (acc[0] + bflo(sv.x)) + bA.x;
        float w1 = d * (acc[1] + bfhi(sv.x)) + bA.y;
        float w2 = d * (acc[2] + bflo(sv.y)) + bA.z;
        float w4 = d * (acc[4] + bflo(sv.z)) + bB.x;
        float w5 = d * (acc[5] + bfhi(sv.z)) + bB.y;
        float w6 = d * (acc[6] + bflo(sv.w)) + bB.z;
        auto wr = [&](int b, float v0, float v1, float v2) {
            int ck = (b < 5) ? 3 : 2;
            float mx = fmaxf(v0, v1);
            if (ck == 3) mx = fmaxf(mx, v2);
            float e0 = __expf(v0 - mx), e1 = __expf(v1 - mx);
            float e2 = (ck == 3) ? __expf(v2 - mx) : 0.0f;
            float inv = 1.0f / (e0 + e1 + e2);
            size_t bb = (b < 5) ? (size_t)b * 3 * N + (size_t)i * 3
                                : (size_t)15 * N + (size_t)(b - 5) * 2 * N + (size_t)i * 2;
            out[bb] = e0 * inv;
            out[bb + 1] = e1 * inv;
            if (ck == 3) out[bb + 2] = e2 * inv;
        };
        wr(sub * 2, w0, w1, w2);
        if (sub < 3) wr(sub * 2 + 1, w4, w5, w6);
    }
}

// ---- launch -------------------------------------------------------------
extern "C" void kernel_launch(void* const* d_in, const int* in_sizes, int n_in,
                              void* d_out, int out_size, void* d_ws, size_t ws_size,
                              hipStream_t stream) {
    (void)n_in; (void)out_size; (void)ws_size;
    const float* x   = (const float*)d_in[0];
    const int*   ei  = (const int*)d_in[1];
    const float* gw  = (const float*)d_in[2];
    const float* gb  = (const float*)d_in[3];
    const float* r3w = (const float*)d_in[4];
    const float* r3b = (const float*)d_in[5];
    const float* r2w = (const float*)d_in[6];
    const float* r2b = (const float*)d_in[7];
    float* out = (float*)d_out;
    int N = in_sizes[0] / H;   // 100000
    int E = in_sizes[1] / 2;   // 1600000
    int NB = (N + 255) >> 8;   // 391 buckets

    char* p = (char*)d_ws;
    auto alloc = [&](size_t bytes) {
        char* q = p;
        p += (bytes + 255) & ~(size_t)255;
        return q;
    };
    unsigned*       xs     = (unsigned*)alloc((size_t)(N + 1) * 64 * 4);  // scaled x bf16, +zero row
    unsigned*       pxb    = (unsigned*)alloc((size_t)N * 64 * 4);
    unsigned short* Wt     = (unsigned short*)alloc((size_t)7 * 16384 * 2);
    unsigned short* WRb    = (unsigned short*)alloc((size_t)14336 * 2);
    float*          bias2  = (float*)alloc(32 * 4);
    int*            bhist  = (int*)alloc(512 * 4);
    int*            bbase  = (int*)alloc(513 * 4);
    int*            gcur   = (int*)alloc(512 * 4);
    int*            tmp_e  = (int*)alloc((size_t)E * 4);
    int*            rp     = (int*)alloc((size_t)(N + 1) * 4);
    float*          dinv   = (float*)alloc((size_t)N * 4);
    int*            csrc   = (int*)alloc((size_t)E * 4);
    float*          uall   = (float*)alloc((size_t)N * 32 * 4);           // fp32 [N,32]
    unsigned*       usb    = (unsigned*)alloc((size_t)(N + 1) * 16 * 4);  // scaled u bf16, +zero row

    hipMemsetAsync(bhist, 0, 512 * 4, stream);
    k_bhist<<<256, 256, 0, stream>>>(ei, bhist, E);
    k_bscan<<<1, 512, 0, stream>>>(bhist, bbase, gcur);
    k_scatter<<<256, 256, 0, stream>>>(ei, gcur, tmp_e, E);
    k_csrAB<<<NB, 256, 0, stream>>>(tmp_e, bbase, rp, dinv, csrc, N, E);
    int prep_threads = N * 64 + 64 + 114688 + 14368;
    k_prep<<<(prep_threads + 255) / 256, 256, 0, stream>>>(x, dinv, xs, N,
            gw, gb, r3w, r3b, r2w, r2b, Wt, WRb, bias2);
    k_px<<<(N + 3) / 4, 256, 0, stream>>>(xs, rp, csrc, dinv, pxb, N);
    dim3 gg((N + 511) / 512, 7);
    k_gemm<<<gg, 256, 0, stream>>>((const unsigned short*)pxb, Wt, gb, WRb, uall, N);
    k_uscale<<<(N * 16 + 16 + 255) / 256, 256, 0, stream>>>(uall, dinv, usb, N);
    k_out<<<(N + 3) / 4, 256, 0, stream>>>(usb, rp, csrc, dinv, bias2, out, N);
}